// Round 1
// baseline (346.074 us; speedup 1.0000x reference)
//
#include <hip/hip_runtime.h>
#include <cstdint>
#include <cmath>

// Binarized MLP via i8 MFMA: 16384x1024 -> 2048 -> 2048 -> 2048 -> 2.
// R5: 256x256 tile, BK=128B, 8 waves (2m x 4n), double-buffered 128KB LDS,
// 4-phase-per-K-tile schedule with raw s_barrier + counted per-wave vmcnt:
// tile t+1's loads issued in phases 0-1 of tile t, drained (vmcnt 0) only at
// end of phase 3 (~3 MFMA phases later -> HBM latency hidden), setprio(1)
// around each MFMA cluster (T3+T4+T5 from the verified 256^2 template).
// Staging keeps the R4 XOR-(row&7) pre-swizzled source (0 bank conflicts).

typedef int i32x4 __attribute__((ext_vector_type(4)));

static constexpr int Bsz = 16384;
static constexpr int Din = 1024;
static constexpr int Hid = 2048;

__device__ __forceinline__ void ld16(const void* g, void* l) {
  __builtin_amdgcn_global_load_lds(
      (const __attribute__((address_space(1))) void*)g,
      (__attribute__((address_space(3))) void*)l, 16, 0, 0);
}

// ---------------- fused prep: all sign-quantizations + BN folds ------------
// blocks [0,16384): x -> A0 (thr 0.5; binq(2x-1)>=0 <=> x>=0.5)
// blocks [16384,18432): w1 -> W1s   [18432,22528): w2 -> W2s
// blocks [22528,26624): w3 -> W3s   [26624,26648): bnprep for 3 layers
__global__ void prep_kernel(
    const float* __restrict__ x, const float* __restrict__ w1,
    const float* __restrict__ w2, const float* __restrict__ w3,
    const float* __restrict__ g1, const float* __restrict__ b1,
    const float* __restrict__ m1, const float* __restrict__ v1,
    const float* __restrict__ g2, const float* __restrict__ b2,
    const float* __restrict__ m2, const float* __restrict__ v2,
    const float* __restrict__ g3, const float* __restrict__ b3,
    const float* __restrict__ m3, const float* __restrict__ v3,
    char* __restrict__ A0, char* __restrict__ W1s,
    char* __restrict__ W2s, char* __restrict__ W3s,
    float* __restrict__ a1, float* __restrict__ be1,
    float* __restrict__ a2, float* __restrict__ be2,
    float* __restrict__ a3, float* __restrict__ be3) {
  constexpr int BX = 16384, BW1 = 2048, BW2 = 4096, BW3 = 4096;
  const int blk = blockIdx.x;
  if (blk < BX + BW1 + BW2 + BW3) {
    const float* s;
    char* d;
    float thr = 0.0f;
    int rb;
    if (blk < BX) {
      s = x; d = A0; thr = 0.5f; rb = 0;
    } else if (blk < BX + BW1) {
      s = w1; d = W1s; rb = BX;
    } else if (blk < BX + BW1 + BW2) {
      s = w2; d = W2s; rb = BX + BW1;
    } else {
      s = w3; d = W3s; rb = BX + BW1 + BW2;
    }
    int i = (blk - rb) * 256 + threadIdx.x;
    float4 v = ((const float4*)s)[i];
    char4 o;
    o.x = (v.x >= thr) ? 1 : -1;
    o.y = (v.y >= thr) ? 1 : -1;
    o.z = (v.z >= thr) ? 1 : -1;
    o.w = (v.w >= thr) ? 1 : -1;
    ((char4*)d)[i] = o;
  } else {
    int t = (blk - (BX + BW1 + BW2 + BW3)) * 256 + threadIdx.x;  // 0..6143
    int l = t >> 11, e = t & 2047;
    const float *g, *b, *m, *v;
    float *al, *be;
    if (l == 0) { g = g1; b = b1; m = m1; v = v1; al = a1; be = be1; }
    else if (l == 1) { g = g2; b = b2; m = m2; v = v2; al = a2; be = be2; }
    else { g = g3; b = b3; m = m3; v = v3; al = a3; be = be3; }
    float a = g[e] / sqrtf(v[e] + 1e-5f);
    al[e] = a;
    be[e] = b[e] - m[e] * a;
  }
}

// ---------------- i8 MFMA layer: C = A x W^T ------------------------------
// Block 256(m) x 256(n) x BK=128 bytes. 8 waves as 2(m) x 4(n); wave tile
// 128x64 = 8x4 mfma 16x16x64 tiles. LDS: 2 buffers x (A 32KB | B 32KB).
// Rows of 128B, 16B-chunk XOR-swizzled by (row&7) at the global source so
// the linear global_load_lds dest holds swizzled data (rule 21).
// Per K-tile: 4 phases (C-quadrant 2mt x 4nt, 16 MFMA each), 2 s_barrier
// per phase, tile t+1 staged during phases 0-1, per-wave vmcnt(0) drain at
// end of phase 3 only.
// FINAL: dot with sign(wout) rows, atomicAdd exact-integer partials (f32).
template <int K, bool FINAL>
__global__ __launch_bounds__(512, 1) void layer_mfma(
    const char* __restrict__ A, const char* __restrict__ W,
    const float* __restrict__ alpha, const float* __restrict__ beta,
    char* __restrict__ O, const float* __restrict__ wout,
    float* __restrict__ out) {
  constexpr int N = Hid;
  constexpr int NT = K / 128;  // K-tiles
  __shared__ __align__(16) char lds[131072];

  const int tid = threadIdx.x;
  const int wave = tid >> 6, lane = tid & 63;

  // grid 512 = 64 mp x 8 np; XCD x owns mp [x*8, x*8+8) for all np.
  const int id = blockIdx.x;
  const int loc = id >> 3;
  const int mp = (id & 7) * 8 + (loc & 7);
  const int np = loc >> 3;
  const int m0 = mp * 256, n0 = np * 256;

  // staging: 4096 chunks of 16B per K-tile (A chunks 0..2047, B 2048..4095).
  // wave w, issue i covers chunks [w*512 + i*64, +64) -> 8 ld16 per lane.
  const char* gp[8];
  int lo[8];
#pragma unroll
  for (int i = 0; i < 8; ++i) {
    int run = wave * 512 + i * 64;            // lane-0 chunk id (uniform)
    bool isA = run < 2048;
    int crun = isA ? run : run - 2048;
    int c = crun + lane;                      // this lane's chunk
    int row = c >> 3;
    int kc = (c & 7) ^ (row & 7);             // pre-swizzled source chunk
    gp[i] = (isA ? A + (size_t)(m0 + row) * K
                 : W + (size_t)(n0 + row) * K) + kc * 16;
    lo[i] = (isA ? 0 : 32768) + crun * 16;    // wave-uniform LDS base
  }

  const int lr = lane & 15, lk = lane >> 4;
  const int wm = wave >> 2, wn = wave & 3;
  const int xs0 = ((0 + lk) ^ (lr & 7)) * 16;  // k-slice 0 chunk slot
  const int xs1 = ((4 + lk) ^ (lr & 7)) * 16;  // k-slice 1 chunk slot
  const int abase = (wm * 128 + lr) * 128;            // + mt*2048 + xs
  const int bbase = 32768 + (wn * 64 + lr) * 128;     // + nt*2048 + xs

  i32x4 acc[8][4] = {};

  // prologue: stage K-tile 0 into buf0, full drain once.
#pragma unroll
  for (int i = 0; i < 8; ++i) {
    ld16(gp[i], lds + lo[i]);
    gp[i] += 128;
  }
  asm volatile("s_waitcnt vmcnt(0)" ::: "memory");
  __builtin_amdgcn_s_barrier();

#pragma unroll 1
  for (int t = 0; t < NT; ++t) {
    const int rb = (t & 1) << 16;   // read buffer
    const int wb = rb ^ 65536;      // write (prefetch) buffer
    const bool pf = (t + 1 < NT);

    // B fragments for the whole K-tile (8 ds_read_b128), read once.
    i32x4 bF[4][2];
#pragma unroll
    for (int nt = 0; nt < 4; ++nt) {
      bF[nt][0] = *(const i32x4*)(lds + rb + bbase + nt * 2048 + xs0);
      bF[nt][1] = *(const i32x4*)(lds + rb + bbase + nt * 2048 + xs1);
    }

#pragma unroll
    for (int q = 0; q < 4; ++q) {
      // quadrant A fragments (4 ds_read_b128)
      i32x4 aF[2][2];
#pragma unroll
      for (int h = 0; h < 2; ++h) {
        const char* ap = lds + rb + abase + (q * 2 + h) * 2048;
        aF[h][0] = *(const i32x4*)(ap + xs0);
        aF[h][1] = *(const i32x4*)(ap + xs1);
      }
      // issue next-tile staging early (phases 0-1), into the other buffer
      if (pf && q < 2) {
#pragma unroll
        for (int i = 0; i < 4; ++i) {
          int j = q * 4 + i;
          ld16(gp[j], lds + wb + lo[j]);
          gp[j] += 128;
        }
      }
      __builtin_amdgcn_s_barrier();
      asm volatile("s_waitcnt lgkmcnt(0)" ::: "memory");
      __builtin_amdgcn_s_setprio(1);
#pragma unroll
      for (int s = 0; s < 2; ++s)
#pragma unroll
        for (int h = 0; h < 2; ++h)
#pragma unroll
          for (int nt = 0; nt < 4; ++nt)
            acc[q * 2 + h][nt] = __builtin_amdgcn_mfma_i32_16x16x64_i8(
                aF[h][s], bF[nt][s], acc[q * 2 + h][nt], 0, 0, 0);
      __builtin_amdgcn_s_setprio(0);
      // end of K-tile: drain own staging loads (issued >=2 phases ago),
      // then barrier so every wave sees the prefetch buffer complete.
      if (q == 3) asm volatile("s_waitcnt vmcnt(0)" ::: "memory");
      __builtin_amdgcn_s_barrier();
    }
  }

  float al[4], be[4];
#pragma unroll
  for (int nt = 0; nt < 4; ++nt) {
    int n = n0 + wn * 64 + nt * 16 + lr;
    al[nt] = alpha[n];
    be[nt] = beta[n];
  }

  if (!FINAL) {
#pragma unroll
    for (int mt = 0; mt < 8; ++mt)
#pragma unroll
      for (int r = 0; r < 4; ++r) {
        int m = m0 + wm * 128 + mt * 16 + lk * 4 + r;  // C/D row=(lane>>4)*4+reg
        char* orow = O + (size_t)m * N;
#pragma unroll
        for (int nt = 0; nt < 4; ++nt) {
          float c = (float)acc[mt][nt][r];
          orow[n0 + wn * 64 + nt * 16 + lr] =
              (fmaf(al[nt], c, be[nt]) >= 0.0f) ? 1 : -1;
        }
      }
  } else {
    int ws0[4], ws1[4];
#pragma unroll
    for (int nt = 0; nt < 4; ++nt) {
      int n = n0 + wn * 64 + nt * 16 + lr;
      ws0[nt] = (wout[n] >= 0.0f) ? 1 : -1;
      ws1[nt] = (wout[2048 + n] >= 0.0f) ? 1 : -1;
    }
#pragma unroll
    for (int mt = 0; mt < 8; ++mt)
#pragma unroll
      for (int r = 0; r < 4; ++r) {
        int m = m0 + wm * 128 + mt * 16 + lk * 4 + r;
        int p0 = 0, p1 = 0;
#pragma unroll
        for (int nt = 0; nt < 4; ++nt) {
          float c = (float)acc[mt][nt][r];
          int a = (fmaf(al[nt], c, be[nt]) >= 0.0f) ? 1 : -1;
          p0 += a * ws0[nt];
          p1 += a * ws1[nt];
        }
        // reduce across lr (lane bits 0..3)
#pragma unroll
        for (int off = 1; off <= 8; off <<= 1) {
          p0 += __shfl_xor(p0, off, 64);
          p1 += __shfl_xor(p1, off, 64);
        }
        if (lr == 0) {
          atomicAdd(&out[m * 2 + 0], (float)p0);
          atomicAdd(&out[m * 2 + 1], (float)p1);
        }
      }
  }
}

extern "C" void kernel_launch(void* const* d_in, const int* in_sizes, int n_in,
                              void* d_out, int out_size, void* d_ws, size_t ws_size,
                              hipStream_t stream) {
  const float* x    = (const float*)d_in[0];
  const float* w1   = (const float*)d_in[1];
  const float* g1   = (const float*)d_in[2];
  const float* b1   = (const float*)d_in[3];
  const float* m1   = (const float*)d_in[4];
  const float* v1   = (const float*)d_in[5];
  const float* w2   = (const float*)d_in[6];
  const float* g2   = (const float*)d_in[7];
  const float* b2   = (const float*)d_in[8];
  const float* m2   = (const float*)d_in[9];
  const float* v2   = (const float*)d_in[10];
  const float* w3   = (const float*)d_in[11];
  const float* g3   = (const float*)d_in[12];
  const float* b3   = (const float*)d_in[13];
  const float* m3   = (const float*)d_in[14];
  const float* v3   = (const float*)d_in[15];
  const float* wout = (const float*)d_in[16];
  float* out = (float*)d_out;

  char* base = (char*)d_ws;
  size_t off = 0;
  auto take = [&](size_t bytes) -> char* {
    char* p = base + off;
    off += (bytes + 255) & ~(size_t)255;
    return p;
  };
  char* A0  = take((size_t)Bsz * Din);
  char* Aa  = take((size_t)Bsz * Hid);
  char* Ab  = take((size_t)Bsz * Hid);
  char* W1s = take((size_t)Hid * Din);
  char* W2s = take((size_t)Hid * Hid);
  char* W3s = take((size_t)Hid * Hid);
  float* a1  = (float*)take(Hid * 4);
  float* be1 = (float*)take(Hid * 4);
  float* a2  = (float*)take(Hid * 4);
  float* be2 = (float*)take(Hid * 4);
  float* a3  = (float*)take(Hid * 4);
  float* be3 = (float*)take(Hid * 4);

  hipMemsetAsync(d_out, 0, (size_t)out_size * sizeof(float), stream);

  prep_kernel<<<26648, 256, 0, stream>>>(
      x, w1, w2, w3,
      g1, b1, m1, v1, g2, b2, m2, v2, g3, b3, m3, v3,
      A0, W1s, W2s, W3s, a1, be1, a2, be2, a3, be3);

  // grid 512: (16384/256) m-panels x (2048/256) n-panels, XCD-swizzled
  layer_mfma<Din, false><<<512, 512, 0, stream>>>(A0, W1s, a1, be1, Aa,
                                                  nullptr, nullptr);
  layer_mfma<Hid, false><<<512, 512, 0, stream>>>(Aa, W2s, a2, be2, Ab,
                                                  nullptr, nullptr);
  layer_mfma<Hid, true><<<512, 512, 0, stream>>>(Ab, W3s, a3, be3, nullptr,
                                                 wout, out);
}